// Round 10
// baseline (79.602 us; speedup 1.0000x reference)
//
// InputLayer Rayleigh-Sommerfeld — round 10: single fused kernel
// (Toeplitz MFMA per |di-si|=a block) + device-scope grid barrier + in-kernel reduce
#include <hip/hip_runtime.h>

namespace rs10 {

constexpr int kN    = 96;
constexpr int kN2   = kN * kN;             // 9216
constexpr int kSlab = 2 * kN2;             // floats per slab (re+im planes)
constexpr unsigned kMagic = 0x5EEDF00Du;   // != 0xAAAAAAAA poison, != 0
constexpr float kScale   = 1.0f / 65536.0f;
constexpr float kUnscale = 65536.0f;

typedef _Float16 f16x8 __attribute__((ext_vector_type(8)));
typedef _Float16 f16x2 __attribute__((ext_vector_type(2)));
typedef float    f32x4 __attribute__((ext_vector_type(4)));

// LDS: ZS 96 rows x 104 halves (pad) | 8 shifted copies x 200 halves x 2 planes
constexpr int kZRow   = 104;
constexpr int kZBytes = kN * kZRow * 2;    // 19968
constexpr int kCopyH  = 200;
constexpr int kWBytes = 8 * kCopyH * 2;    // 3200 per plane

__global__ __launch_bounds__(256) void rs_fused_v10(const float* __restrict__ img,
                                                    float* __restrict__ slabs,
                                                    unsigned* __restrict__ flags,
                                                    float* __restrict__ out) {
    const float dl      = (float)(1e-3 / 96.0);
    const float dz      = 0.01f;
    const float dz2     = dz * dz;
    const float lam_amp = (float)(1.0 / 1.55e-6);
    const float inv_2pi = 1.0f / 6.2831855f;
    const float k32     = 6.2831855f / 1.55e-6f;   // fp32(2pi)/fp32(lambda)

    __shared__ __align__(16) unsigned char lds[kZBytes + 2 * kWBytes];
    _Float16* ZS  = (_Float16*)lds;
    _Float16* WRe = (_Float16*)(lds + kZBytes);
    _Float16* WIm = (_Float16*)(lds + kZBytes + kWBytes);
    __shared__ float smax[4];

    const int a   = (int)blockIdx.x;               // row offset |di-si|
    const int tid = (int)threadIdx.x;
    const int lane = tid & 63, wid = tid >> 6;

    // ---- max(img), float4 loads (exact fp32 max, matches reference) ----
    float vmax = 0.0f;
    for (int t = tid; t < kN2 / 4; t += 256) {
        const float4 v = ((const float4*)img)[t];
        vmax = fmaxf(vmax, fmaxf(fmaxf(v.x, v.y), fmaxf(v.z, v.w)));
    }
    for (int off = 32; off >= 1; off >>= 1) vmax = fmaxf(vmax, __shfl_xor(vmax, off, 64));
    if (lane == 0) smax[wid] = vmax;

    // ---- table row W[a][c], 8 shift-replicated reversed copies (validated r9) ----
    if (tid < 191) {
        const float ax = (float)a * dl;
        const float by = (float)(tid - 95) * dl;
        const float r  = sqrtf(ax * ax + by * by + dz2);
        const float theta = k32 * r;               // fp32-rounded phase (as reference)
        const float sn = sinf(theta);
        const float cs = cosf(theta);
        const float rinv = 1.0f / r;
        const float ampf = dz * rinv * rinv;
        const float nearf = rinv * inv_2pi;
        const _Float16 hre = (_Float16)(ampf * (nearf * cs + lam_amp * sn) * kScale);
        const _Float16 him = (_Float16)(ampf * (nearf * sn - lam_amp * cs) * kScale);
        const int cp = 190 - tid;
#pragma unroll
        for (int s = 0; s < 8; ++s) {
            const int q = cp - s;
            if (q >= 0) {
                WRe[s * kCopyH + q] = hre;
                WIm[s * kCopyH + q] = him;
            }
        }
    }

    // ---- Z_a rows in fp16 (validated r9) ----
    for (int idx = tid; idx < kN * 48; idx += 256) {
        const int m  = idx / 48;
        const int c2 = idx - m * 48;
        float vx = 0.0f, vy = 0.0f;
        const int r1 = m - a, r2 = m + a;
        if (r1 >= 0) {
            const float2 t = ((const float2*)(img + r1 * kN))[c2];
            vx += t.x; vy += t.y;
        }
        if (a > 0 && r2 < kN) {
            const float2 t = ((const float2*)(img + r2 * kN))[c2];
            vx += t.x; vy += t.y;
        }
        f16x2 h; h.x = (_Float16)vx; h.y = (_Float16)vy;
        *(f16x2*)(ZS + m * kZRow + c2 * 2) = h;
    }
    __syncthreads();
    const float gmax = fmaxf(fmaxf(smax[0], smax[1]), fmaxf(smax[2], smax[3]));

    // ---- MFMA (validated r9) ----
    const int quad = lane >> 4, l15 = lane & 15;
    const int wr = wid >> 1, wc = wid & 1;

    const f32x4 vzero = {0.0f, 0.0f, 0.0f, 0.0f};
    f32x4 acc[3][3][2];
#pragma unroll
    for (int mi = 0; mi < 3; ++mi)
#pragma unroll
        for (int ni = 0; ni < 3; ++ni) { acc[mi][ni][0] = vzero; acc[mi][ni][1] = vzero; }

    for (int kt = 0; kt < 3; ++kt) {
        const int k0 = kt * 32 + quad * 8;
        f16x8 afrag[3];
#pragma unroll
        for (int mi = 0; mi < 3; ++mi) {
            const int m = (wr * 3 + mi) * 16 + l15;
            afrag[mi] = *(const f16x8*)(ZS + m * kZRow + k0);
        }
#pragma unroll
        for (int ni = 0; ni < 3; ++ni) {
            const int n = (wc * 3 + ni) * 16 + l15;
            const int p = 95 + k0 - n;
            const int s = p & 7;
            const int off = s * kCopyH + (p - s);
            const f16x8 bre = *(const f16x8*)(WRe + off);
            const f16x8 bim = *(const f16x8*)(WIm + off);
#pragma unroll
            for (int mi = 0; mi < 3; ++mi) {
                acc[mi][ni][0] = __builtin_amdgcn_mfma_f32_16x16x32_f16(afrag[mi], bre, acc[mi][ni][0], 0, 0, 0);
                acc[mi][ni][1] = __builtin_amdgcn_mfma_f32_16x16x32_f16(afrag[mi], bim, acc[mi][ni][1], 0, 0, 0);
            }
        }
    }

    // ---- write this a's partial to its slab ----
    float* slab = slabs + (size_t)a * kSlab;
#pragma unroll
    for (int mi = 0; mi < 3; ++mi) {
#pragma unroll
        for (int ni = 0; ni < 3; ++ni) {
            const int dj = (wc * 3 + ni) * 16 + l15;
#pragma unroll
            for (int rg = 0; rg < 4; ++rg) {
                const int di = (wr * 3 + mi) * 16 + quad * 4 + rg;
                slab[di * kN + dj]       = acc[mi][ni][0][rg];
                slab[kN2 + di * kN + dj] = acc[mi][ni][1][rg];
            }
        }
    }

    // ---- grid barrier: release own slab, announce, wait for all 96 ----
    __syncthreads();                                        // all block stores drained (vmcnt0)
    __builtin_amdgcn_fence(__ATOMIC_RELEASE, "agent");      // L2 writeback -> device scope
    if (tid == 0)
        __hip_atomic_store(&flags[a], kMagic, __ATOMIC_RELAXED, __HIP_MEMORY_SCOPE_AGENT);
    if (tid < kN) {
        while (__hip_atomic_load(&flags[tid], __ATOMIC_RELAXED, __HIP_MEMORY_SCOPE_AGENT) != kMagic)
            __builtin_amdgcn_s_sleep(8);
    }
    __syncthreads();
    __builtin_amdgcn_fence(__ATOMIC_ACQUIRE, "agent");      // invalidate local caches

    // ---- reduce: block a owns 192 outputs; coalesced across tid ----
    if (tid < 192) {
        const int g = a * 192 + tid;                        // 0..18431 (planar re|im)
        float s0 = 0.0f, s1 = 0.0f, s2 = 0.0f, s3 = 0.0f;
#pragma unroll
        for (int s = 0; s < kN; s += 4) {
            s0 += slabs[(size_t)(s + 0) * kSlab + g];
            s1 += slabs[(size_t)(s + 1) * kSlab + g];
            s2 += slabs[(size_t)(s + 2) * kSlab + g];
            s3 += slabs[(size_t)(s + 3) * kSlab + g];
        }
        out[g] = ((s0 + s1) + (s2 + s3)) * (kUnscale / gmax);
    }
}

}  // namespace rs10

extern "C" void kernel_launch(void* const* d_in, const int* in_sizes, int n_in,
                              void* d_out, int out_size, void* d_ws, size_t ws_size,
                              hipStream_t stream) {
    (void)in_sizes; (void)n_in; (void)out_size; (void)ws_size;
    const float* img = (const float*)d_in[0];
    float* slabs = (float*)d_ws;                                   // 96 * 73728 B = 7.08 MB
    unsigned* flags = (unsigned*)((char*)d_ws + (8u << 20));       // at +8 MB, any init ok
    float* out = (float*)d_out;
    hipLaunchKernelGGL(rs10::rs_fused_v10, dim3(rs10::kN), dim3(256), 0, stream,
                       img, slabs, flags, out);
}

// Round 11
// 70.577 us; speedup vs baseline: 1.1279x; 1.1279x over previous
//
// InputLayer Rayleigh-Sommerfeld — round 11: REVERT to round-8 structure (empirical best).
// fp16-packed shift-invariant table, ds_read2-pairable taps, scalar weight loads,
// per-split slab accumulation + reduce kernel (no atomics, no memset).
// Rationale: rounds 7-10 show dur_us is dominated by the harness's 268 MB d_ws
// re-poison fill (~41 us @ ~6.6 TB/s) + ~20-25 us replay overhead; kernel-side
// work is ~10 us. r8 is the measured minimum (70.7 us); r9 (73.2) and r10 (79.6)
// regressed within/beyond noise. This is a confirm-the-floor reversion.
#include <hip/hip_runtime.h>

namespace rs11 {

constexpr int kN    = 96;
constexpr int kN2   = kN * kN;          // 9216
constexpr int kOut2 = 2 * kN2;          // 18432 floats (planar re/im)
constexpr int kDetPerBlock = 256;
constexpr int kDetBlocks   = kN2 / kDetPerBlock;  // 36
constexpr int kSiPerBlock  = 4;
constexpr int kSplits      = kN / kSiPerBlock;    // 24
constexpr int kGrid  = kDetBlocks * kSplits;      // 864
constexpr int kBlock = 256;
constexpr int kCols  = 2 * kN - 1;      // 191
constexpr int kMaxRows = 8;             // |di-si| row span per block <= 7
constexpr float kScale    = 1.0f / 65536.0f;   // fp16 range scaling for W
constexpr float kUnscale  = 65536.0f;

typedef _Float16 half2_t __attribute__((ext_vector_type(2)));

__global__ __launch_bounds__(kBlock) void rs_conv_v11(const float* __restrict__ img,
                                                      float* __restrict__ ws) {
    const float dl      = (float)(1e-3 / 96.0);
    const float dz      = 0.01f;
    const float dz2     = dz * dz;
    const float lam_amp = (float)(1.0 / 1.55e-6);
    const float inv_2pi = 1.0f / 6.2831855f;
    const float k32     = 6.2831855f / 1.55e-6f;   // fp32(2pi)/fp32(lambda)

    __shared__ half2_t tab[kMaxRows * kCols];

    const int tid = (int)threadIdx.x;
    const int db  = (int)blockIdx.x / kSplits;     // detector tile
    const int ss  = (int)blockIdx.x % kSplits;     // source split
    const int d0  = db * kDetPerBlock;
    const int di_lo = d0 / kN;
    const int di_hi = (d0 + kDetPerBlock - 1) / kN;
    const int si_lo = ss * kSiPerBlock;
    const int si_hi = si_lo + kSiPerBlock - 1;

    int amin;
    if (di_lo <= si_hi && si_lo <= di_hi) amin = 0;
    else amin = (di_lo > si_hi) ? (di_lo - si_hi) : (si_lo - di_hi);
    const int amax  = max(di_hi - si_lo, si_hi - di_lo);
    const int nrows = amax - amin + 1;             // <= 8

    // ---- build fp16-packed table slice with accurate libm ----
    for (int e = tid; e < nrows * kCols; e += kBlock) {
        const int ra = e / kCols;
        const int c  = e - ra * kCols;
        const float ax = (float)(amin + ra) * dl;
        const float by = (float)(c - (kN - 1)) * dl;
        const float r  = sqrtf(ax * ax + by * by + dz2);
        const float theta = k32 * r;               // fp32-rounded phase, as reference
        const float sn = sinf(theta);
        const float cs = cosf(theta);
        const float rinv = 1.0f / r;
        const float ampf = dz * rinv * rinv;
        const float near = rinv * inv_2pi;
        const float wre = ampf * (near * cs + lam_amp * sn);
        const float wim = ampf * (near * sn - lam_amp * cs);
        half2_t h;
        h.x = (_Float16)(wre * kScale);
        h.y = (_Float16)(wim * kScale);
        tab[e] = h;
    }
    __syncthreads();

    // ---- one thread per detector ----
    const int det = d0 + tid;
    const int di  = det / kN;
    const int dj  = det - di * kN;

    float acc_re = 0.0f, acc_im = 0.0f;

#pragma unroll
    for (int sl = 0; sl < kSiPerBlock; ++sl) {
        const int si = si_lo + sl;
        int av = di - si;
        if (av < 0) av = -av;
        const half2_t* __restrict__ rp = tab + (av - amin) * kCols + dj;
        const float2*  __restrict__ xw = (const float2*)(img + si * kN);  // uniform addr
#pragma unroll
        for (int t = 0; t < kN / 2; ++t) {
            const float2  x2 = xw[t];                 // weights (x[si][2t], x[si][2t+1])
            const half2_t wa = rp[(kN - 1) - 2 * t];  // tap sj = 2t
            const half2_t wb = rp[(kN - 2) - 2 * t];  // tap sj = 2t+1 (adjacent dword)
            acc_re = fmaf((float)wa.x, x2.x, acc_re);
            acc_im = fmaf((float)wa.y, x2.x, acc_im);
            acc_re = fmaf((float)wb.x, x2.y, acc_re);
            acc_im = fmaf((float)wb.y, x2.y, acc_im);
        }
    }

    // private slab per split — no atomics, no zero-init needed
    float* slab = ws + (size_t)ss * kOut2;
    slab[det]       = acc_re;
    slab[kN2 + det] = acc_im;
}

__global__ __launch_bounds__(kBlock) void rs_reduce_v11(const float* __restrict__ img,
                                                        const float* __restrict__ ws,
                                                        float* __restrict__ out) {
    const int tid = (int)threadIdx.x;
    const int g   = (int)blockIdx.x * kBlock + tid;   // 0..18431

    // block-wide max over img (uniform[0,1): 0 is a safe identity)
    float vmax = 0.0f;
    for (int t = tid; t < kN2; t += kBlock) vmax = fmaxf(vmax, img[t]);
    for (int off = 32; off >= 1; off >>= 1) vmax = fmaxf(vmax, __shfl_xor(vmax, off, 64));
    __shared__ float smax[4];
    if ((tid & 63) == 0) smax[tid >> 6] = vmax;
    __syncthreads();
    const float gmax  = fmaxf(fmaxf(smax[0], smax[1]), fmaxf(smax[2], smax[3]));
    const float scale = kUnscale / gmax;              // undo fp16 scaling + 1/max

    float s0 = 0.0f, s1 = 0.0f, s2 = 0.0f, s3 = 0.0f;
#pragma unroll
    for (int s = 0; s < kSplits; s += 4) {
        s0 += ws[(size_t)(s + 0) * kOut2 + g];
        s1 += ws[(size_t)(s + 1) * kOut2 + g];
        s2 += ws[(size_t)(s + 2) * kOut2 + g];
        s3 += ws[(size_t)(s + 3) * kOut2 + g];
    }
    out[g] = ((s0 + s1) + (s2 + s3)) * scale;
}

}  // namespace rs11

extern "C" void kernel_launch(void* const* d_in, const int* in_sizes, int n_in,
                              void* d_out, int out_size, void* d_ws, size_t ws_size,
                              hipStream_t stream) {
    (void)in_sizes; (void)n_in; (void)out_size; (void)ws_size;
    const float* img = (const float*)d_in[0];
    float* ws  = (float*)d_ws;
    float* out = (float*)d_out;
    hipLaunchKernelGGL(rs11::rs_conv_v11, dim3(rs11::kGrid), dim3(rs11::kBlock), 0, stream,
                       img, ws);
    hipLaunchKernelGGL(rs11::rs_reduce_v11, dim3(rs11::kOut2 / rs11::kBlock), dim3(rs11::kBlock),
                       0, stream, img, ws, out);
}